// Round 6
// baseline (69.955 us; speedup 1.0000x reference)
//
#include <hip/hip_runtime.h>
#include <math.h>

// x: (16,3,448,448) fp32; 14x14 patches -> Hp=Wp=32; 3x3 DCT over 12x12 sliding windows
// out: (16,32,32) fp32
//
// Block = 8 consecutive patches x 3 channels, 192 threads, grid 2048 (all resident:
// 8 blocks/CU x 3 waves = 24 waves/CU). Window pass: 576 half-row runs (6 windows)
// per block, 3 per thread. Lane mapping is ROW-COALESCED: each 16-lane group covers
// one global image row (8 patches x 2 halves), so a wave-level load touches ~18
// cache lines instead of ~50 (fixes L1 gather serialization seen in r4/r5).

typedef unsigned int uint32;

__device__ __forceinline__ float fsqrt_fast(float x) { return __builtin_amdgcn_sqrtf(x); } // v_sqrt_f32
__device__ __forceinline__ float frcp_fast(float x)  { return __builtin_amdgcn_rcpf(x);  } // v_rcp_f32
__device__ __forceinline__ float flog2_fast(float x) { return __builtin_amdgcn_logf(x);  } // v_log_f32

__device__ __forceinline__ float std3_fast(float a, float b, float c) {
    // ddof=0 std of 3 via E[x^2]-E[x]^2 (clamped)
    float s = a + b + c;
    float q = fmaf(a, a, fmaf(b, b, c * c));
    float v = fmaf(q, (1.0f / 3.0f), (s * s) * (-1.0f / 9.0f));
    return fsqrt_fast(fmaxf(v, 0.0f));
}

__global__ __launch_bounds__(192, 8) void richness_kernel(
    const float* __restrict__ x,
    const float* __restrict__ dctm,
    float* __restrict__ out)
{
    const int bid = blockIdx.x;       // b*128 + hp*4 + wpg
    const int wpg = bid & 3;          // group of 8 patches along wp
    const int hp  = (bid >> 2) & 31;
    const int b   = bid >> 7;
    const int tid = threadIdx.x;

    __shared__ uint32 hist[6][256];      // 4 pcs per word, u8 counts (max 196, no carry)
    __shared__ float  psiPart[24][24];   // [pc][task = wi*2+half]
    __shared__ float  entAcc[24];
    __shared__ float  richAcc[24];

    // DCT structure: row0 = k0*(1,1,1); row1 = k1*(1,0,-1) (D[1][1]~6e-17); row2 = k2*(1,-2,1)
    const float k0 = dctm[0];
    const float k1 = dctm[3];
    const float k2 = dctm[6];

    for (int i = tid; i < 6 * 256; i += 192) ((uint32*)hist)[i] = 0u;
    __syncthreads();

    // ---- coalesced histogram pass (also warms L1/L2) ----
    for (int t = tid; t < 1176; t += 192) {          // 3ch * 14 rows * 28 float4
        int ch  = t / 392;                           // 392 = 14*28
        int rem = t - ch * 392;
        int row = rem / 28;
        int col = (rem - row * 28) * 4;
        const float* src = x + (((size_t)(b * 3 + ch) * 448 + hp * 14 + row) * 448) + wpg * 112 + col;
        float4 v = *reinterpret_cast<const float4*>(src);
#pragma unroll
        for (int e = 0; e < 4; ++e) {
            float val = (&v.x)[e];
            int bin = (int)rintf(val * 255.0f);      // round-half-even == np.round
            bin = min(max(bin, 0), 255);
            int ce = col + e;
            int p  = (ce * 2341) >> 15;              // ce/14 for ce<112
            int pc = ch * 8 + p;
            atomicAdd(&hist[pc >> 2][bin], 1u << ((pc & 3) * 8));
        }
    }
    // no sync needed: window pass doesn't touch hist; atomics drain under compute

    // ---- window pass: 3 runs of 6 windows, row-coalesced lane mapping ----
#pragma unroll 1
    for (int kr = 0; kr < 3; ++kr) {
        int rho    = tid + 192 * kr;     // 0..575
        int row_id = rho >> 4;           // 0..35 : (ch, wi)
        int l16    = rho & 15;           // 0..15 : (p, half)
        int ch     = (row_id * 2731) >> 15;   // row_id / 12
        int wi     = row_id - ch * 12;
        int p      = l16 >> 1;
        int half   = l16 & 1;

        const float* base = x + (((size_t)(b * 3 + ch) * 448 + hp * 14 + wi) * 448)
                              + wpg * 112 + p * 14 + half * 6;

        // 12 float2 loads: 3 rows (0,+448,+896) x 4 float2 (8 cols); all offsets
        // fold into 13-bit load immediates from one base.
        float r0[8], r1[8], r2[8];
#pragma unroll
        for (int c2 = 0; c2 < 4; ++c2) {
            float2 a  = *reinterpret_cast<const float2*>(base + c2 * 2);
            float2 bb = *reinterpret_cast<const float2*>(base + 448 + c2 * 2);
            float2 cv = *reinterpret_cast<const float2*>(base + 896 + c2 * 2);
            r0[c2 * 2] = a.x;  r0[c2 * 2 + 1] = a.y;
            r1[c2 * 2] = bb.x; r1[c2 * 2 + 1] = bb.y;
            r2[c2 * 2] = cv.x; r2[c2 * 2 + 1] = cv.y;
        }

        // vertical DCT triples for 8 columns
        float t0[8], t1[8], t2[8];
#pragma unroll
        for (int J = 0; J < 8; ++J) {
            float s = r0[J] + r2[J];
            t0[J] = k0 * (s + r1[J]);
            t1[J] = k1 * (r0[J] - r2[J]);
            t2[J] = k2 * fmaf(-2.0f, r1[J], s);
        }

        float psi_run = 0.0f;
#pragma unroll
        for (int m = 0; m < 6; ++m) {
            float X0 = t0[m],     X1 = t1[m],     X2 = t2[m];
            float Y0 = t0[m + 1], Y1 = t1[m + 1], Y2 = t2[m + 1];
            float Z0 = t0[m + 2], Z1 = t1[m + 2], Z2 = t2[m + 2];
            float xz0 = X0 + Z0, xz1 = X1 + Z1, xz2 = X2 + Z2;
            float d00 = k0 * (xz0 + Y0), d01 = k1 * (X0 - Z0), d02 = k2 * fmaf(-2.0f, Y0, xz0);
            float d10 = k0 * (xz1 + Y1), d11 = k1 * (X1 - Z1), d12 = k2 * fmaf(-2.0f, Y1, xz1);
            float d20 = k0 * (xz2 + Y2), d21 = k1 * (X2 - Z2), d22 = k2 * fmaf(-2.0f, Y2, xz2);

            float S1 = (std3_fast(d00, d01, d02) + std3_fast(d10, d11, d12) + std3_fast(d20, d21, d22)) * (1.0f / 3.0f);
            float S2 = (std3_fast(d00, d10, d20) + std3_fast(d01, d11, d21) + std3_fast(d02, d12, d22)) * (1.0f / 3.0f);
            float S3 = std3_fast(d00, d11, d22);
            float S4 = std3_fast(d02, d11, d20);

            float sumS = (S1 + S2) + (S3 + S4);
            float sumQ = fmaf(S1, S1, fmaf(S2, S2, fmaf(S3, S3, S4 * S4)));
            float h    = fmaxf(fmaf(-0.25f * sumS, sumS, sumQ), 0.0f);
            float Sm   = fmaf(sumS, 0.25f, 1e-8f);
            float inv  = frcp_fast(Sm);
            psi_run    = fmaf(h * inv * inv, (1.0f / 3.0f), psi_run);
        }
        psiPart[ch * 8 + p][wi * 2 + half] = psi_run;
    }
    __syncthreads();   // psiPart written AND hist atomics drained

    // ---- entropy: 8 threads per pc, 32 bins each ----
    {
        const int pcE = tid >> 3, sub = tid & 7;
        const int rowW = pcE >> 2, sh = (pcE & 3) * 8;
        float negent = 0.0f;
#pragma unroll
        for (int kk = 0; kk < 32; ++kk) {
            uint32 c = (hist[rowW][sub + 8 * kk] >> sh) & 0xffu;
            float pr = (float)c * (1.0f / 196.0f) + 1e-10f;
            negent = fmaf(pr, flog2_fast(pr), negent);
        }
#pragma unroll
        for (int off = 1; off < 8; off <<= 1) negent += __shfl_xor(negent, off, 64);
        if (sub == 0) entAcc[pcE] = -negent;
    }
    __syncthreads();

    // ---- per-pc psi sum + richness ----
    if (tid < 24) {
        float s = 0.0f;
#pragma unroll
        for (int r = 0; r < 24; ++r) s += psiPart[tid][r];
        richAcc[tid] = (s * (1.0f / 144.0f)) * entAcc[tid];
    }
    __syncthreads();

    // ---- channel mean -> out ----
    if (tid < 8) {
        float rv = (richAcc[tid] + richAcc[8 + tid] + richAcc[16 + tid]) * (1.0f / 3.0f);
        out[(b * 32 + hp) * 32 + wpg * 8 + tid] = rv;
    }
}

extern "C" void kernel_launch(void* const* d_in, const int* in_sizes, int n_in,
                              void* d_out, int out_size, void* d_ws, size_t ws_size,
                              hipStream_t stream) {
    const float* x    = (const float*)d_in[0];
    const float* dctm = (const float*)d_in[1];
    float* out        = (float*)d_out;

    richness_kernel<<<2048, 192, 0, stream>>>(x, dctm, out);
}

// Round 8
// 48.081 us; speedup vs baseline: 1.4549x; 1.4549x over previous
//
#include <hip/hip_runtime.h>
#include <math.h>

// x: (16,3,448,448) fp32; 14x14 patches -> Hp=Wp=32; 3x3 DCT over 12x12 sliding windows
// out: (16,32,32) fp32
//
// Block = 8 consecutive patches x 3 channels, 576 threads (9 waves), grid 2048.
// Each thread does EXACTLY ONE half-row run of 6 windows (576 runs/block = 576 thr):
// no outer loop, no tail, shallow per-thread pipeline. 3 blocks/CU = 27 waves/CU
// (84% of the 32-wave cap) -- fixes r4's 36% occupancy while keeping r4's math
// (1.33 vertical-DCT triples/window, float2 loads with immediate offsets).

typedef unsigned int uint32;

__device__ __forceinline__ float fsqrt_fast(float x) { return __builtin_amdgcn_sqrtf(x); } // v_sqrt_f32
__device__ __forceinline__ float frcp_fast(float x)  { return __builtin_amdgcn_rcpf(x);  } // v_rcp_f32
__device__ __forceinline__ float flog2_fast(float x) { return __builtin_amdgcn_logf(x);  } // v_log_f32

__device__ __forceinline__ float std3_fast(float a, float b, float c) {
    // ddof=0 std of 3 via E[x^2]-E[x]^2 (clamped)
    float s = a + b + c;
    float q = fmaf(a, a, fmaf(b, b, c * c));
    float v = fmaf(q, (1.0f / 3.0f), (s * s) * (-1.0f / 9.0f));
    return fsqrt_fast(fmaxf(v, 0.0f));
}

__global__ __launch_bounds__(576, 7) void richness_kernel(
    const float* __restrict__ x,
    const float* __restrict__ dctm,
    float* __restrict__ out)
{
    const int bid = blockIdx.x;       // b*128 + hp*4 + wpg
    const int wpg = bid & 3;          // group of 8 patches along wp
    const int hp  = (bid >> 2) & 31;
    const int b   = bid >> 7;
    const int tid = threadIdx.x;

    __shared__ uint32 hist[6][256];      // 24 pcs, u8 x4-packed (max count 196, no carry)
    __shared__ float  psiPart[24][24];   // [pc][task = wi*2+half]
    __shared__ float  entAcc[24];
    __shared__ float  richAcc[24];

    // DCT structure: row0 = k0*(1,1,1); row1 = k1*(1,0,-1) (D[1][1]~6e-17); row2 = k2*(1,-2,1)
    const float k0 = dctm[0];
    const float k1 = dctm[3];
    const float k2 = dctm[6];

    for (int i = tid; i < 6 * 256; i += 576) ((uint32*)hist)[i] = 0u;
    __syncthreads();

    // ---- coalesced histogram pass (also warms L1/L2 for the window pass) ----
    for (int t = tid; t < 1176; t += 576) {          // 3ch * 14 rows * 28 float4
        int ch  = t / 392;                           // 392 = 14*28
        int rem = t - ch * 392;
        int row = rem / 28;
        int col = (rem - row * 28) * 4;
        const float* src = x + (((size_t)(b * 3 + ch) * 448 + hp * 14 + row) * 448) + wpg * 112 + col;
        float4 v = *reinterpret_cast<const float4*>(src);
#pragma unroll
        for (int e = 0; e < 4; ++e) {
            float val = (&v.x)[e];
            int bin = (int)rintf(val * 255.0f);      // round-half-even == np.round
            bin = min(max(bin, 0), 255);
            int ce = col + e;
            int p  = (ce * 2341) >> 15;              // ce/14 for ce<112
            int pc = ch * 8 + p;
            atomicAdd(&hist[pc >> 2][bin], 1u << ((pc & 3) * 8));
        }
    }
    // no sync needed: window pass doesn't read hist; atomics drain under compute

    // ---- window pass: ONE run of 6 windows per thread ----
    {
        const int pc   = tid / 24;       // 0..23
        const int rr   = tid - pc * 24;  // 0..23
        const int ch   = pc >> 3, p = pc & 7;
        const int wi   = rr >> 1, half = rr & 1;
        const float* base = x + (((size_t)(b * 3 + ch) * 448 + hp * 14 + wi) * 448)
                              + wpg * 112 + p * 14 + half * 6;

        // 12 float2 loads: 3 rows (0,+448,+896) x 4 float2 (8 cols); offsets fold
        // into 13-bit load immediates from one base address.
        float r0[8], r1[8], r2[8];
#pragma unroll
        for (int c2 = 0; c2 < 4; ++c2) {
            float2 a  = *reinterpret_cast<const float2*>(base + c2 * 2);
            float2 bb = *reinterpret_cast<const float2*>(base + 448 + c2 * 2);
            float2 cv = *reinterpret_cast<const float2*>(base + 896 + c2 * 2);
            r0[c2 * 2] = a.x;  r0[c2 * 2 + 1] = a.y;
            r1[c2 * 2] = bb.x; r1[c2 * 2 + 1] = bb.y;
            r2[c2 * 2] = cv.x; r2[c2 * 2 + 1] = cv.y;
        }

        // vertical DCT triples for 8 columns
        float t0[8], t1[8], t2[8];
#pragma unroll
        for (int J = 0; J < 8; ++J) {
            float s = r0[J] + r2[J];
            t0[J] = k0 * (s + r1[J]);
            t1[J] = k1 * (r0[J] - r2[J]);
            t2[J] = k2 * fmaf(-2.0f, r1[J], s);
        }

        float psi_run = 0.0f;
#pragma unroll
        for (int m = 0; m < 6; ++m) {
            float X0 = t0[m],     X1 = t1[m],     X2 = t2[m];
            float Y0 = t0[m + 1], Y1 = t1[m + 1], Y2 = t2[m + 1];
            float Z0 = t0[m + 2], Z1 = t1[m + 2], Z2 = t2[m + 2];
            float xz0 = X0 + Z0, xz1 = X1 + Z1, xz2 = X2 + Z2;
            float d00 = k0 * (xz0 + Y0), d01 = k1 * (X0 - Z0), d02 = k2 * fmaf(-2.0f, Y0, xz0);
            float d10 = k0 * (xz1 + Y1), d11 = k1 * (X1 - Z1), d12 = k2 * fmaf(-2.0f, Y1, xz1);
            float d20 = k0 * (xz2 + Y2), d21 = k1 * (X2 - Z2), d22 = k2 * fmaf(-2.0f, Y2, xz2);

            float S1 = (std3_fast(d00, d01, d02) + std3_fast(d10, d11, d12) + std3_fast(d20, d21, d22)) * (1.0f / 3.0f);
            float S2 = (std3_fast(d00, d10, d20) + std3_fast(d01, d11, d21) + std3_fast(d02, d12, d22)) * (1.0f / 3.0f);
            float S3 = std3_fast(d00, d11, d22);
            float S4 = std3_fast(d02, d11, d20);

            float sumS = (S1 + S2) + (S3 + S4);
            float sumQ = fmaf(S1, S1, fmaf(S2, S2, fmaf(S3, S3, S4 * S4)));
            float h    = fmaxf(fmaf(-0.25f * sumS, sumS, sumQ), 0.0f);
            float Sm   = fmaf(sumS, 0.25f, 1e-8f);
            float inv  = frcp_fast(Sm);
            psi_run    = fmaf(h * inv * inv, (1.0f / 3.0f), psi_run);
        }
        psiPart[pc][rr] = psi_run;
    }
    __syncthreads();   // psiPart written AND hist atomics drained

    // ---- entropy: 16 threads per pc, 16 bins each (tid < 384 active) ----
    if (tid < 384) {
        const int pcE = tid >> 4, sub = tid & 15;
        const int rowW = pcE >> 2, sh = (pcE & 3) * 8;
        float negent = 0.0f;
#pragma unroll
        for (int kk = 0; kk < 16; ++kk) {
            uint32 c = (hist[rowW][sub + 16 * kk] >> sh) & 0xffu;
            float pr = (float)c * (1.0f / 196.0f) + 1e-10f;
            negent = fmaf(pr, flog2_fast(pr), negent);
        }
#pragma unroll
        for (int off = 1; off < 16; off <<= 1) negent += __shfl_xor(negent, off, 64);
        if (sub == 0) entAcc[pcE] = -negent;
    }
    __syncthreads();

    // ---- per-pc psi sum + richness ----
    if (tid < 24) {
        float s = 0.0f;
#pragma unroll
        for (int r = 0; r < 24; ++r) s += psiPart[tid][r];
        richAcc[tid] = (s * (1.0f / 144.0f)) * entAcc[tid];
    }
    __syncthreads();

    // ---- channel mean -> out ----
    if (tid < 8) {
        float rv = (richAcc[tid] + richAcc[8 + tid] + richAcc[16 + tid]) * (1.0f / 3.0f);
        out[(b * 32 + hp) * 32 + wpg * 8 + tid] = rv;
    }
}

extern "C" void kernel_launch(void* const* d_in, const int* in_sizes, int n_in,
                              void* d_out, int out_size, void* d_ws, size_t ws_size,
                              hipStream_t stream) {
    const float* x    = (const float*)d_in[0];
    const float* dctm = (const float*)d_in[1];
    float* out        = (float*)d_out;

    richness_kernel<<<2048, 576, 0, stream>>>(x, dctm, out);
}

// Round 9
// 38.603 us; speedup vs baseline: 1.8122x; 1.2455x over previous
//
#include <hip/hip_runtime.h>
#include <math.h>

// x: (16,3,448,448) fp32; 14x14 patches -> Hp=Wp=32; 3x3 DCT over 12x12 sliding windows
// out: (16,32,32) fp32
//
// r4 structure (block = 8 patches x 3 ch, 192 thr, 3 half-row runs of 6 windows each,
// grid 2048) + software pipelining: the histogram loads are issued in pairs UNDER the
// window-run compute, so the block-start HBM latency (r4's ~10us low-busy phase)
// hides beneath VALU work. All loads in named registers (no runtime-indexed arrays).

typedef unsigned int uint32;

__device__ __forceinline__ float fsqrt_fast(float x) { return __builtin_amdgcn_sqrtf(x); } // v_sqrt_f32
__device__ __forceinline__ float frcp_fast(float x)  { return __builtin_amdgcn_rcpf(x);  } // v_rcp_f32
__device__ __forceinline__ float flog2_fast(float x) { return __builtin_amdgcn_logf(x);  } // v_log_f32

__device__ __forceinline__ float std3_fast(float a, float b, float c) {
    // ddof=0 std of 3 via E[x^2]-E[x]^2 (clamped)
    float s = a + b + c;
    float q = fmaf(a, a, fmaf(b, b, c * c));
    float v = fmaf(q, (1.0f / 3.0f), (s * s) * (-1.0f / 9.0f));
    return fsqrt_fast(fmaxf(v, 0.0f));
}

struct RunData {
    float2 a0, a1, a2, a3, b0, b1, b2, b3, c0, c1, c2, c3;
};

__device__ __forceinline__ RunData load_run(const float* base) {
    RunData r;
    r.a0 = *reinterpret_cast<const float2*>(base + 0);
    r.a1 = *reinterpret_cast<const float2*>(base + 2);
    r.a2 = *reinterpret_cast<const float2*>(base + 4);
    r.a3 = *reinterpret_cast<const float2*>(base + 6);
    r.b0 = *reinterpret_cast<const float2*>(base + 448);
    r.b1 = *reinterpret_cast<const float2*>(base + 450);
    r.b2 = *reinterpret_cast<const float2*>(base + 452);
    r.b3 = *reinterpret_cast<const float2*>(base + 454);
    r.c0 = *reinterpret_cast<const float2*>(base + 896);
    r.c1 = *reinterpret_cast<const float2*>(base + 898);
    r.c2 = *reinterpret_cast<const float2*>(base + 900);
    r.c3 = *reinterpret_cast<const float2*>(base + 902);
    return r;
}

__device__ __forceinline__ float run_psi(const RunData& rd, float k0, float k1, float k2) {
    float r0[8] = { rd.a0.x, rd.a0.y, rd.a1.x, rd.a1.y, rd.a2.x, rd.a2.y, rd.a3.x, rd.a3.y };
    float r1[8] = { rd.b0.x, rd.b0.y, rd.b1.x, rd.b1.y, rd.b2.x, rd.b2.y, rd.b3.x, rd.b3.y };
    float r2[8] = { rd.c0.x, rd.c0.y, rd.c1.x, rd.c1.y, rd.c2.x, rd.c2.y, rd.c3.x, rd.c3.y };

    // vertical DCT triples for 8 columns (fully unrolled -> constant indices)
    float t0[8], t1[8], t2[8];
#pragma unroll
    for (int J = 0; J < 8; ++J) {
        float s = r0[J] + r2[J];
        t0[J] = k0 * (s + r1[J]);
        t1[J] = k1 * (r0[J] - r2[J]);
        t2[J] = k2 * fmaf(-2.0f, r1[J], s);
    }

    float psi_run = 0.0f;
#pragma unroll
    for (int m = 0; m < 6; ++m) {
        float X0 = t0[m],     X1 = t1[m],     X2 = t2[m];
        float Y0 = t0[m + 1], Y1 = t1[m + 1], Y2 = t2[m + 1];
        float Z0 = t0[m + 2], Z1 = t1[m + 2], Z2 = t2[m + 2];
        float xz0 = X0 + Z0, xz1 = X1 + Z1, xz2 = X2 + Z2;
        float d00 = k0 * (xz0 + Y0), d01 = k1 * (X0 - Z0), d02 = k2 * fmaf(-2.0f, Y0, xz0);
        float d10 = k0 * (xz1 + Y1), d11 = k1 * (X1 - Z1), d12 = k2 * fmaf(-2.0f, Y1, xz1);
        float d20 = k0 * (xz2 + Y2), d21 = k1 * (X2 - Z2), d22 = k2 * fmaf(-2.0f, Y2, xz2);

        float S1 = (std3_fast(d00, d01, d02) + std3_fast(d10, d11, d12) + std3_fast(d20, d21, d22)) * (1.0f / 3.0f);
        float S2 = (std3_fast(d00, d10, d20) + std3_fast(d01, d11, d21) + std3_fast(d02, d12, d22)) * (1.0f / 3.0f);
        float S3 = std3_fast(d00, d11, d22);
        float S4 = std3_fast(d02, d11, d20);

        float sumS = (S1 + S2) + (S3 + S4);
        float sumQ = fmaf(S1, S1, fmaf(S2, S2, fmaf(S3, S3, S4 * S4)));
        float h    = fmaxf(fmaf(-0.25f * sumS, sumS, sumQ), 0.0f);
        float Sm   = fmaf(sumS, 0.25f, 1e-8f);
        float inv  = frcp_fast(Sm);
        psi_run    = fmaf(h * inv * inv, (1.0f / 3.0f), psi_run);
    }
    return psi_run;
}

__global__ __launch_bounds__(192, 6) void richness_kernel(
    const float* __restrict__ x,
    const float* __restrict__ dctm,
    float* __restrict__ out)
{
    const int bid = blockIdx.x;       // b*128 + hp*4 + wpg
    const int wpg = bid & 3;          // group of 8 patches along wp
    const int hp  = (bid >> 2) & 31;
    const int b   = bid >> 7;
    const int tid = threadIdx.x;

    __shared__ uint32 hist[6][256];      // 24 pcs, u8 x4-packed (max count 196, no carry)
    __shared__ float  psiPart[24][24];   // [pc][task = wi*2+half]
    __shared__ float  entAcc[24];
    __shared__ float  richAcc[24];

    // DCT structure: row0 = k0*(1,1,1); row1 = k1*(1,0,-1) (D[1][1]~6e-17); row2 = k2*(1,-2,1)
    const float k0 = dctm[0];
    const float k1 = dctm[3];
    const float k2 = dctm[6];

    for (int i = tid; i < 6 * 256; i += 192) ((uint32*)hist)[i] = 0u;
    __syncthreads();

    // ---- run bases (3 half-row runs of 6 windows per thread) ----
    int pcA[3], rrA[3];
    const float* rbase[3];
#pragma unroll
    for (int kr = 0; kr < 3; ++kr) {
        int rho = tid + 192 * kr;        // 0..575
        int pc  = rho / 24;
        int rr  = rho - pc * 24;
        pcA[kr] = pc; rrA[kr] = rr;
        int ch = pc >> 3, p = pc & 7;
        int wi = rr >> 1, half = rr & 1;
        rbase[kr] = x + (((size_t)(b * 3 + ch) * 448 + hp * 14 + wi) * 448)
                      + wpg * 112 + p * 14 + half * 6;
    }

    // ---- hist task addresses: t = tid + 192*i, i = 0..5 (1152 of 1176 float4s) ----
#define HTASK(i, CH, COL, SRC) \
    int CH, COL; const float* SRC; { \
        int t_   = tid + 192 * (i); \
        CH       = t_ / 392;                  /* 392 = 14*28 */ \
        int rem_ = t_ - CH * 392; \
        int row_ = rem_ / 28; \
        COL      = (rem_ - row_ * 28) * 4; \
        SRC      = x + (((size_t)(b * 3 + CH) * 448 + hp * 14 + row_) * 448) + wpg * 112 + COL; }

#define BIN4(V, CH, COL) { \
        _Pragma("unroll") \
        for (int e_ = 0; e_ < 4; ++e_) { \
            float val_ = (&(V).x)[e_]; \
            int bin_ = (int)rintf(val_ * 255.0f);   /* round-half-even == np.round */ \
            bin_ = min(max(bin_, 0), 255); \
            int ce_ = (COL) + e_; \
            int p_  = (ce_ * 2341) >> 15;           /* ce/14 for ce<112 */ \
            int pc_ = (CH) * 8 + p_; \
            atomicAdd(&hist[pc_ >> 2][bin_], 1u << ((pc_ & 3) * 8)); \
        }}

    HTASK(0, ch0, col0, src0) HTASK(1, ch1, col1, src1)
    HTASK(2, ch2, col2, src2) HTASK(3, ch3, col3, src3)
    HTASK(4, ch4, col4, src4) HTASK(5, ch5, col5, src5)

    // ---- pipelined: run loads -> hist-pair loads -> run compute -> bin pair ----
    // run0: hide h0,h1
    RunData rd0 = load_run(rbase[0]);
    float4 h0 = *reinterpret_cast<const float4*>(src0);
    float4 h1 = *reinterpret_cast<const float4*>(src1);
    float psi0 = run_psi(rd0, k0, k1, k2);
    psiPart[pcA[0]][rrA[0]] = psi0;
    BIN4(h0, ch0, col0)
    BIN4(h1, ch1, col1)

    // run1: hide h2,h3
    float4 h2 = *reinterpret_cast<const float4*>(src2);
    float4 h3 = *reinterpret_cast<const float4*>(src3);
    RunData rd1 = load_run(rbase[1]);
    float psi1 = run_psi(rd1, k0, k1, k2);
    psiPart[pcA[1]][rrA[1]] = psi1;
    BIN4(h2, ch2, col2)
    BIN4(h3, ch3, col3)

    // run2: hide h4,h5
    float4 h4 = *reinterpret_cast<const float4*>(src4);
    float4 h5 = *reinterpret_cast<const float4*>(src5);
    RunData rd2 = load_run(rbase[2]);
    float psi2 = run_psi(rd2, k0, k1, k2);
    psiPart[pcA[2]][rrA[2]] = psi2;
    BIN4(h4, ch4, col4)
    BIN4(h5, ch5, col5)

    // tail: float4 tasks 1152..1175 -> uniformly ch=2, row=13, col=(4+tid)*4
    if (tid < 24) {
        int colT = (4 + tid) * 4;
        const float* srcT = x + (((size_t)(b * 3 + 2) * 448 + hp * 14 + 13) * 448) + wpg * 112 + colT;
        float4 hT = *reinterpret_cast<const float4*>(srcT);
        BIN4(hT, 2, colT)
    }
#undef HTASK
#undef BIN4
    __syncthreads();   // psiPart written AND hist atomics drained

    // ---- entropy: 8 threads per pc, 32 bins each ----
    {
        const int pcE = tid >> 3, sub = tid & 7;
        const int rowW = pcE >> 2, sh = (pcE & 3) * 8;
        float negent = 0.0f;
#pragma unroll
        for (int kk = 0; kk < 32; ++kk) {
            uint32 c = (hist[rowW][sub + 8 * kk] >> sh) & 0xffu;
            float pr = (float)c * (1.0f / 196.0f) + 1e-10f;
            negent = fmaf(pr, flog2_fast(pr), negent);
        }
#pragma unroll
        for (int off = 1; off < 8; off <<= 1) negent += __shfl_xor(negent, off, 64);
        if (sub == 0) entAcc[pcE] = -negent;
    }
    __syncthreads();

    // ---- per-pc psi sum + richness ----
    if (tid < 24) {
        float s = 0.0f;
#pragma unroll
        for (int r = 0; r < 24; ++r) s += psiPart[tid][r];
        richAcc[tid] = (s * (1.0f / 144.0f)) * entAcc[tid];
    }
    __syncthreads();

    // ---- channel mean -> out ----
    if (tid < 8) {
        float rv = (richAcc[tid] + richAcc[8 + tid] + richAcc[16 + tid]) * (1.0f / 3.0f);
        out[(b * 32 + hp) * 32 + wpg * 8 + tid] = rv;
    }
}

extern "C" void kernel_launch(void* const* d_in, const int* in_sizes, int n_in,
                              void* d_out, int out_size, void* d_ws, size_t ws_size,
                              hipStream_t stream) {
    const float* x    = (const float*)d_in[0];
    const float* dctm = (const float*)d_in[1];
    float* out        = (float*)d_out;

    richness_kernel<<<2048, 192, 0, stream>>>(x, dctm, out);
}